// Round 7
// baseline (64.649 us; speedup 1.0000x reference)
//
#include <hip/hip_runtime.h>

// DMLoss: B=1024, Np=Ng=128, T=10.
// Round 7: single fused kernel, FENCE-FREE cross-block finish.
//  - Round 3's regression traced to per-block __threadfence() (L1-inv storm),
//    not atomics. Here: 3 u64 fixed-point atomicAdds per block; ordering vs
//    the ticket atomic enforced by a DATA DEPENDENCY on their returned values
//    (empty asm consumes them -> vmcnt drain -> RMWs performed at coherence
//    point before ticket issues). Last ticket reads accs via atomicAdd(p,0).
//    Integer adds commute -> bit-deterministic across graph replays.
//  - Epilogue split: waves 0-1 combine part 1 (l_a), waves 2-3 combine part 2
//    (l_c,l_m) -> half the serial combine latency, fewer shuffle chains.
//  - Scan phase unchanged from round 6 (proved non-dominant).

constexpr int NP = 128;
constexpr int NG = 128;

__global__ __launch_bounds__(512) void dm_fused(
    const float* __restrict__ ini,   // [B, NP, 2]
    const float* __restrict__ pp,    // [B, NP, 2]
    const float* __restrict__ gt,    // [B, NG, 2]
    const float* __restrict__ mask,  // [B, NG]
    unsigned long long* __restrict__ acc,  // [0..2] fixed-point sums, [3] ticket
    float* __restrict__ out, int nblocks, double inv_count)
{
    const int b   = blockIdx.x;
    const int tid = threadIdx.x;

    __shared__ float2 s_gt [NG];
    __shared__ float2 s_ini[NP];
    __shared__ float2 s_pp [NP];
    __shared__ float4 s_seg[NG];       // {pv.x, pv.y, ex, ey}
    __shared__ float4 s_r1 [8][64];    // {d0, i0, d1, i1}
    __shared__ float4 s_r2 [8][64];
    __shared__ float  s_red[6];        // a(w0),a(w1),c(w2),m(w2),c(w3),m(w3)

    const float2* gtb  = (const float2*)(gt  + (size_t)b * 256);
    const float2* inib = (const float2*)(ini + (size_t)b * 256);
    const float2* ppb  = (const float2*)(pp  + (size_t)b * 256);

    // Staging (no LDS deps before the barrier)
    if (tid < 128) {
        const float2 cv = gtb[tid];
        const float2 pv = gtb[(tid + 127) & 127];
        s_gt [tid] = cv;
        s_seg[tid] = make_float4(pv.x, pv.y, cv.x - pv.x, cv.y - pv.y);
    } else if (tid < 256) {
        s_ini[tid - 128] = inib[tid - 128];
    } else if (tid < 384) {
        s_pp [tid - 256] = ppb[tid - 256];
    }

    const int pr = tid & 63;           // point-pair index
    const int g  = tid >> 6;           // group 0..7 (wave-uniform)
    const float2 q0 = inib[pr];        // part-1 queries (L1-hot)
    const float2 q1 = inib[pr + 64];
    const float2 g0 = gtb [pr];        // part-2 queries
    const float2 g1 = gtb [pr + 64];
    const float  mval = (tid < 256) ? mask[(size_t)b * NG + (tid & 127)] : 0.0f;
    __syncthreads();

    // ---- Part 1 scan: 16 segments x 2 points per thread ----
    {
        float bd0 = 3.4e38f, bi0 = 0.0f, bd1 = 3.4e38f, bi1 = 0.0f;
        float basef = (float)(g * 160);
        const int s0 = g * 16;
        #pragma unroll
        for (int k = 0; k < 16; ++k) {
            const float4 sg = s_seg[s0 + k];    // broadcast ds_read_b128
            const float ex = sg.z, ey = sg.w;
            const float ee  = fmaxf(fmaf(ex, ex, ey * ey), 1e-30f);
            const float s10 = 10.0f * __builtin_amdgcn_rcpf(ee);
            {
                const float wx = q0.x - sg.x, wy = q0.y - sg.y;
                float tc = rintf(fmaf(wy, ey, wx * ex) * s10);
                tc = __builtin_amdgcn_fmed3f(tc, 0.0f, 9.0f);
                const float u   = tc * 0.1f;    // model distance only
                const float dqx = fmaf(-u, ex, wx);
                const float dqy = fmaf(-u, ey, wy);
                const float d   = fmaf(dqy, dqy, dqx * dqx);
                bi0 = (d < bd0) ? (basef + tc) : bi0;  // strict <: first occurrence
                bd0 = fminf(d, bd0);
            }
            {
                const float wx = q1.x - sg.x, wy = q1.y - sg.y;
                float tc = rintf(fmaf(wy, ey, wx * ex) * s10);
                tc = __builtin_amdgcn_fmed3f(tc, 0.0f, 9.0f);
                const float u   = tc * 0.1f;
                const float dqx = fmaf(-u, ex, wx);
                const float dqy = fmaf(-u, ey, wy);
                const float d   = fmaf(dqy, dqy, dqx * dqx);
                bi1 = (d < bd1) ? (basef + tc) : bi1;
                bd1 = fminf(d, bd1);
            }
            basef += 10.0f;
        }
        s_r1[g][pr] = make_float4(bd0, bi0, bd1, bi1);
    }

    // ---- Part 2 scan: 16 preds x 2 gt vertices per thread ----
    {
        float bd0 = 3.4e38f, bj0 = 0.0f, bd1 = 3.4e38f, bj1 = 0.0f;
        float jf = (float)(g * 16);
        const int j0 = g * 16;
        #pragma unroll
        for (int k = 0; k < 16; ++k) {
            const float2 pv = s_ini[j0 + k];    // broadcast ds_read_b64
            {
                const float dx = g0.x - pv.x, dy = g0.y - pv.y;
                const float d  = fmaf(dy, dy, dx * dx);
                bj0 = (d < bd0) ? jf : bj0;
                bd0 = fminf(d, bd0);
            }
            {
                const float dx = g1.x - pv.x, dy = g1.y - pv.y;
                const float d  = fmaf(dy, dy, dx * dx);
                bj1 = (d < bd1) ? jf : bj1;
                bd1 = fminf(d, bd1);
            }
            jf += 1.0f;
        }
        s_r2[g][pr] = make_float4(bd0, bj0, bd1, bj1);
    }
    __syncthreads();

    // ---- Split combine: waves 0-1 -> part 1 (l_a); waves 2-3 -> part 2 ----
    float l_a = 0.0f, l_c = 0.0f, l_m = 0.0f;
    if (tid < 128) {
        const int slot = tid >> 6;              // wave-uniform
        const int ln   = tid & 63;
        float bd = 3.4e38f, bi = 0.0f;
        #pragma unroll
        for (int gg = 0; gg < 8; ++gg) {
            const float4 r  = s_r1[gg][ln];     // coalesced ds_read_b128
            const float d2 = slot ? r.z : r.x;
            const float i2 = slot ? r.w : r.y;
            bi = (d2 < bd) ? i2 : bi;
            bd = fminf(d2, bd);
        }
        const int idx = (int)bi;
        const int n = idx / 10;                 // magic-mul
        const int t = idx - n * 10;
        const float step = (float)t / 10.0f;    // exact ref: arange(T)/T
        const float om   = 1.0f - step;
        const float2 c   = s_gt[n];
        const float2 prv = s_gt[(n + NG - 1) & (NG - 1)];
        const float nx = c.x * step + prv.x * om;
        const float ny = c.y * step + prv.y * om;
        const float2 mp = s_pp[tid];
        l_a = fabsf(mp.x - nx) + fabsf(mp.y - ny);
    } else if (tid < 256) {
        const int v    = tid - 128;             // gt vertex
        const int slot = v >> 6;                // wave-uniform
        const int ln   = v & 63;
        float cd = 3.4e38f, cj = 0.0f;
        #pragma unroll
        for (int gg = 0; gg < 8; ++gg) {
            const float4 r  = s_r2[gg][ln];
            const float d2 = slot ? r.z : r.x;
            const float j2 = slot ? r.w : r.y;
            cj = (d2 < cd) ? j2 : cj;
            cd = fminf(d2, cd);
        }
        const float2 npt = s_pp[(int)cj];
        const float2 gvv = s_gt[v];
        l_c = mval * (fabsf(npt.x - gvv.x) + fabsf(npt.y - gvv.y));
        l_m = 2.0f * mval;
    }

    const int wid = tid >> 6, lane = tid & 63;
    if (wid < 2) {
        for (int off = 32; off > 0; off >>= 1) l_a += __shfl_down(l_a, off);
        if (lane == 0) s_red[wid] = l_a;
    } else if (wid < 4) {
        for (int off = 32; off > 0; off >>= 1) {
            l_c += __shfl_down(l_c, off);
            l_m += __shfl_down(l_m, off);
        }
        if (lane == 0) { s_red[2 * wid - 2] = l_c; s_red[2 * wid - 1] = l_m; }
    }
    __syncthreads();

    if (tid == 0) {
        const double FPS = 4294967296.0;   // 2^32 fixed-point scale
        const double a = (double)s_red[0] + (double)s_red[1];
        const double c = (double)s_red[2] + (double)s_red[4];
        const double m = (double)s_red[3] + (double)s_red[5];
        unsigned long long o0 = atomicAdd(&acc[0], (unsigned long long)llrint(a * FPS));
        unsigned long long o1 = atomicAdd(&acc[1], (unsigned long long)llrint(c * FPS));
        unsigned long long o2 = atomicAdd(&acc[2], (unsigned long long)llrint(m * FPS));
        // Data-dependency fence: consuming the returned values forces vmcnt
        // drain (RMWs performed at coherence point) before the ticket issues.
        asm volatile("" :: "v"(o0), "v"(o1), "v"(o2) : "memory");
        const unsigned long long tick = atomicAdd(&acc[3], 1ull);
        if (tick == (unsigned long long)(nblocks - 1)) {
            const double at = (double)atomicAdd(&acc[0], 0ull) / FPS;
            const double ct = (double)atomicAdd(&acc[1], 0ull) / FPS;
            const double mt = (double)atomicAdd(&acc[2], 0ull) / FPS;
            const double loss = ct / (mt + 1.0) + at * inv_count;
            out[0] = (float)(loss * 0.5);
        }
    }
}

extern "C" void kernel_launch(void* const* d_in, const int* in_sizes, int n_in,
                              void* d_out, int out_size, void* d_ws, size_t ws_size,
                              hipStream_t stream) {
    const float* ini  = (const float*)d_in[0];
    const float* pp   = (const float*)d_in[1];
    const float* gt   = (const float*)d_in[2];
    const float* mask = (const float*)d_in[3];

    const int B = in_sizes[0] / (NP * 2);
    unsigned long long* acc = (unsigned long long*)d_ws;

    // d_ws is not re-poisoned between replays: re-zero the 4 accumulators
    // each call (tiny graph-capturable memset node).
    hipMemsetAsync(d_ws, 0, 4 * sizeof(unsigned long long), stream);

    const double inv_count = 1.0 / ((double)B * NP * 2);
    dm_fused<<<B, 512, 0, stream>>>(ini, pp, gt, mask, acc, (float*)d_out, B, inv_count);
}

// Round 8
// 18.448 us; speedup vs baseline: 3.5044x; 3.5044x over previous
//
#include <hip/hip_runtime.h>

// DMLoss: B=1024, Np=Ng=128, T=10.
// Round 8: two-kernel (cross-block atomics cost ~40us: rounds 3/7 — same-line
// RMW serialization, not fences). Changes vs round 4/6:
//  - LDS tables PADDED (idx i+(i>>5)): the 4 quarters' reads {k,32+k,64+k,96+k}
//    previously hit the same bank quad -> 4-way conflict (the constant 21263
//    SQ_LDS_BANK_CONFLICT seen in rounds 3-7). Now distinct banks.
//  - A point's 4 quarter-scans live in ONE wave (lane = quarter*16+sub):
//    argmin combine = 2 shfl_xor steps with index tie-break. Deletes s_r1/s_r2
//    LDS round-trip, the 2nd barrier, the separate combine phase, and the
//    redundant per-thread global query loads.
//  - SoA partials -> coalesced dm_final.

constexpr int NP = 128;
constexpr int NG = 128;

__device__ __forceinline__ int padi(int i) { return i + (i >> 5); }

__global__ __launch_bounds__(512) void dm_main(
    const float* __restrict__ ini,   // [B, NP, 2]
    const float* __restrict__ pp,    // [B, NP, 2]
    const float* __restrict__ gt,    // [B, NG, 2]
    const float* __restrict__ mask,  // [B, NG]
    float* __restrict__ partial,     // SoA: [3][B]
    int nb)
{
    const int b    = blockIdx.x;
    const int tid  = threadIdx.x;
    const int lane = tid & 63;
    const int w    = tid >> 6;             // wave 0..7

    __shared__ float2 s_gt [NG];           // epilogue random gathers (unpadded)
    __shared__ float4 s_seg[NG + 4];       // padded: {pv.x, pv.y, ex, ey}
    __shared__ float  s_s10[NG + 4];       // padded: 10/|e|^2
    __shared__ float2 s_ini[NP + 4];       // padded
    __shared__ float2 s_pp [NP];           // random gather (unpadded)
    __shared__ float  s_red[24];

    const float2* gtb  = (const float2*)(gt  + (size_t)b * 256);
    const float2* inib = (const float2*)(ini + (size_t)b * 256);
    const float2* ppb  = (const float2*)(pp  + (size_t)b * 256);

    // Staging (no LDS dependencies before the barrier)
    if (tid < 128) {
        const float2 cv = gtb[tid];
        const float2 pv = gtb[(tid + 127) & 127];
        const float ex = cv.x - pv.x, ey = cv.y - pv.y;
        s_gt [tid]       = cv;
        s_seg[padi(tid)] = make_float4(pv.x, pv.y, ex, ey);
        const float ee = fmaxf(fmaf(ex, ex, ey * ey), 1e-30f);
        s_s10[padi(tid)] = 10.0f * __builtin_amdgcn_rcpf(ee);
    } else if (tid < 256) {
        const int i = tid - 128;
        s_ini[padi(i)] = inib[i];
    } else if (tid < 384) {
        s_pp[tid - 256] = ppb[tid - 256];
    }

    const int sub     = lane & 15;         // point/vertex within wave's 16
    const int quarter = lane >> 4;         // 0..3
    const int pnt     = (w << 4) | sub;    // 0..127 (wave w owns points w*16..+16)
    float mval = 0.0f;
    if (quarter == 0) mval = mask[(size_t)b * NG + pnt];   // early, hidden
    __syncthreads();

    const float2 q  = s_ini[padi(pnt)];    // 16 distinct addrs -> conflict-free
    const float2 gv = s_gt[pnt];

    // ---- Part 1 scan: segments [quarter*32, +32) for point pnt ----
    float bd1 = 3.4e38f, bi1 = 0.0f;
    {
        const int s0 = quarter << 5;
        float basef = (float)(s0 * 10);
        #pragma unroll 8
        for (int k = 0; k < 32; ++k) {
            const float4 sg  = s_seg[padi(s0 + k)];   // distinct banks per quarter
            const float  s10 = s_s10[padi(s0 + k)];
            const float wx = q.x - sg.x, wy = q.y - sg.y;
            float tc = rintf(fmaf(wy, sg.w, wx * sg.z) * s10);
            tc = __builtin_amdgcn_fmed3f(tc, 0.0f, 9.0f);
            const float u   = tc * 0.1f;              // model distance only
            const float dqx = fmaf(-u, sg.z, wx);
            const float dqy = fmaf(-u, sg.w, wy);
            const float d   = fmaf(dqy, dqy, dqx * dqx);
            const float cand = basef + tc;
            bi1 = (d < bd1) ? cand : bi1;             // strict <: first occurrence
            bd1 = fminf(d, bd1);
            basef += 10.0f;
        }
    }

    // ---- Part 2 scan: preds [quarter*32, +32) for gt vertex pnt ----
    float bd2 = 3.4e38f, bj2 = 0.0f;
    {
        const int j0 = quarter << 5;
        float jf = (float)j0;
        #pragma unroll 8
        for (int k = 0; k < 32; ++k) {
            const float2 pv = s_ini[padi(j0 + k)];
            const float dx = gv.x - pv.x, dy = gv.y - pv.y;
            const float d  = fmaf(dy, dy, dx * dx);
            bj2 = (d < bd2) ? jf : bj2;
            bd2 = fminf(d, bd2);
            jf += 1.0f;
        }
    }

    // ---- In-wave combine over quarters (lane bits 4,5); tie -> lower index.
    // Quarter order == index order, so (d==d_o && i_o<i) gives jnp.argmin
    // first-occurrence exactly.
    #pragma unroll
    for (int st = 16; st <= 32; st <<= 1) {
        const float d1o = __shfl_xor(bd1, st);
        const float i1o = __shfl_xor(bi1, st);
        const bool  t1  = (d1o < bd1) || (d1o == bd1 && i1o < bi1);
        bi1 = t1 ? i1o : bi1;
        bd1 = t1 ? d1o : bd1;
        const float d2o = __shfl_xor(bd2, st);
        const float j2o = __shfl_xor(bj2, st);
        const bool  t2  = (d2o < bd2) || (d2o == bd2 && j2o < bj2);
        bj2 = t2 ? j2o : bj2;
        bd2 = t2 ? d2o : bd2;
    }

    // ---- Epilogue on quarter-0 lanes (each holds the full-argmin result) ----
    float l_a = 0.0f, l_c = 0.0f, l_m = 0.0f;
    if (quarter == 0) {
        const int idx = (int)bi1;
        const int n = idx / 10;                      // magic-mul
        const int t = idx - n * 10;
        const float step = (float)t / 10.0f;         // exact ref: arange(T)/T
        const float om   = 1.0f - step;
        const float2 c   = s_gt[n];
        const float2 prv = s_gt[(n + NG - 1) & (NG - 1)];
        const float nx = c.x * step + prv.x * om;
        const float ny = c.y * step + prv.y * om;
        const float2 mp = s_pp[pnt];
        l_a = fabsf(mp.x - nx) + fabsf(mp.y - ny);

        const float2 npt = s_pp[(int)bj2];
        l_c = mval * (fabsf(npt.x - gv.x) + fabsf(npt.y - gv.y));
        l_m = 2.0f * mval;
    }

    // Reduce the 16 quarter-0 lanes (others carry zeros): bits 0..3
    #pragma unroll
    for (int st = 1; st <= 8; st <<= 1) {
        l_a += __shfl_xor(l_a, st);
        l_c += __shfl_xor(l_c, st);
        l_m += __shfl_xor(l_m, st);
    }
    if (lane == 0) {
        s_red[w * 3 + 0] = l_a;
        s_red[w * 3 + 1] = l_c;
        s_red[w * 3 + 2] = l_m;
    }
    __syncthreads();
    if (tid < 3) {
        float s = 0.0f;
        #pragma unroll
        for (int ww = 0; ww < 8; ++ww) s += s_red[ww * 3 + tid];
        partial[(size_t)tid * nb + b] = s;           // SoA -> coalesced final
    }
}

__global__ __launch_bounds__(256) void dm_final(
    const float* __restrict__ partial, int nb, double inv_count, float* __restrict__ out)
{
    const int tid = threadIdx.x;
    double a = 0.0, c = 0.0, d = 0.0;
    for (int i = tid; i < nb; i += 256) {            // 3 coalesced streams
        a += (double)partial[i];
        c += (double)partial[(size_t)nb + i];
        d += (double)partial[(size_t)2 * nb + i];
    }
    for (int off = 32; off > 0; off >>= 1) {
        a += __shfl_down(a, off);
        c += __shfl_down(c, off);
        d += __shfl_down(d, off);
    }
    __shared__ double s[12];
    const int wid = tid >> 6, lane = tid & 63;
    if (lane == 0) { s[wid * 3] = a; s[wid * 3 + 1] = c; s[wid * 3 + 2] = d; }
    __syncthreads();
    if (tid == 0) {
        const double at = s[0] + s[3] + s[6] + s[9];
        const double ct = s[1] + s[4] + s[7] + s[10];
        const double dt = s[2] + s[5] + s[8] + s[11];
        const double loss = ct / (dt + 1.0) + at * inv_count;
        out[0] = (float)(loss * 0.5);
    }
}

extern "C" void kernel_launch(void* const* d_in, const int* in_sizes, int n_in,
                              void* d_out, int out_size, void* d_ws, size_t ws_size,
                              hipStream_t stream) {
    const float* ini  = (const float*)d_in[0];
    const float* pp   = (const float*)d_in[1];
    const float* gt   = (const float*)d_in[2];
    const float* mask = (const float*)d_in[3];
    float* out = (float*)d_out;

    const int B = in_sizes[0] / (NP * 2);
    float* partial = (float*)d_ws;                   // 3*B floats

    dm_main<<<B, 512, 0, stream>>>(ini, pp, gt, mask, partial, B);
    const double inv_count = 1.0 / ((double)B * NP * 2);
    dm_final<<<1, 256, 0, stream>>>(partial, B, inv_count, out);
}